// Round 18
// baseline (34.109 us; speedup 1.0000x reference)
//
#include <hip/hip_runtime.h>

// Problem constants (fixed by the reference)
#define S_N 32
#define O_N 64
#define A_N 8
#define R_N 8
#define B_N 1024
#define T_N 128

// LDS emission block offsets (floats): OT[o][s] | RA[r*8+a][s] | RT[r][s] | PI[s]
#define L_OT 0
#define L_RA 2048
#define L_RT 4096
#define L_PI 4352
#define L_N  4384

typedef float f32x4 __attribute__((ext_vector_type(4)));
typedef short bf16x8 __attribute__((ext_vector_type(8)));

#define RLI(v, l) __builtin_amdgcn_readlane((v), (l))

// v_cvt_pk_bf16_f32: dst = (bf16(lo) low16, bf16(hi) high16) — r17-validated
static __device__ __forceinline__ int cvtpk(float lo, float hi) {
    int r;
    asm("v_cvt_pk_bf16_f32 %0, %1, %2" : "=v"(r) : "v"(lo), "v"(hi));
    return r;
}

union U8 { int i[4]; bf16x8 v; };

__global__ __launch_bounds__(256) void tam_fused(
    const float* __restrict__ regime,
    const int*   __restrict__ obs,
    const int*   __restrict__ rewards,
    const int*   __restrict__ dones_i,   // float32 0/1 read as int bits
    const int*   __restrict__ actions,
    const float* __restrict__ params_s,
    const float* __restrict__ params_s_sa,
    const float* __restrict__ params_o_s,
    const float* __restrict__ params_r_s,
    const float* __restrict__ params_a_s,
    float* __restrict__ out)
{
    // sTH: T in MFMA fragment layout with permuted k (r16-validated bytes):
    //   entry[(a*2+f)*64 + l] elem j = T[pi(8*(l>>4)+j)][a][(l&15)+16f]
    //   pi(8g+2m) = 4g+m ; pi(8g+2m+1) = 4g+m+16
    // Consumed as the A operand: lane l holds A row (l&15)+16f, k-octet l>>4.
    __shared__ __align__(16) uint4 sTH[1024];   // 16 KB
    __shared__ __align__(16) float sE[L_N];     // 17.1 KB
    __shared__ float sAT[256];
    const int tid  = threadIdx.x;
    const int lane = tid & 63;
    const int wid  = tid >> 6;
    const int g    = lane >> 4;
    const int c0   = 4 * g;              // this lane's low-state group base
    const int c1   = 4 * g + 16;
    const int b    = blockIdx.x * 4 + wid;
    const f32x4 zf4 = {0.f, 0.f, 0.f, 0.f};

    // ---------- Phase 1: build tables in LDS (r16-validated) ----------
    if (tid < 128) {
        unsigned short* sTHh = reinterpret_cast<unsigned short*>(sTH);
        #pragma unroll 1
        for (int rr = 0; rr < 2; ++rr) {
            const int idx = 2 * tid + rr;
            const int s = idx >> 3, a = idx & 7;
            const float* row = params_s_sa + (s * A_N + a) * S_N;
            float p[32];
            #pragma unroll
            for (int i = 0; i < 8; ++i) {
                float4 v = reinterpret_cast<const float4*>(row)[i];
                p[4*i]=v.x; p[4*i+1]=v.y; p[4*i+2]=v.z; p[4*i+3]=v.w;
            }
            float mx = p[0];
            #pragma unroll
            for (int i = 1; i < 32; ++i) mx = fmaxf(mx, p[i]);
            float sum = 0.f;
            #pragma unroll
            for (int i = 0; i < 32; ++i) { p[i] = __expf(p[i] - mx); sum += p[i]; }
            const float inv = 1.0f / sum;
            const int ks = 2 * (s & 15) + (s >> 4);   // permuted k-slot of row s
            const int gk = ks >> 3, e8 = ks & 7;
            #pragma unroll
            for (int d = 0; d < 32; ++d) {
                const unsigned bits = __float_as_uint(p[d] * inv) + 0x8000u;
                const int l2 = 16 * gk + (d & 15);
                sTHh[((a * 2 + (d >> 4)) * 64 + l2) * 8 + e8] =
                    (unsigned short)(bits >> 16);
            }
        }
    } else {
        const int e = tid - 128;
        if (e < 32) {
            const int s = e;
            const float* row = params_o_s + s * O_N;
            float p[64];
            #pragma unroll
            for (int i = 0; i < 16; ++i) {
                float4 v = reinterpret_cast<const float4*>(row)[i];
                p[4*i]=v.x; p[4*i+1]=v.y; p[4*i+2]=v.z; p[4*i+3]=v.w;
            }
            float mx = p[0];
            #pragma unroll
            for (int i = 1; i < 64; ++i) mx = fmaxf(mx, p[i]);
            float sum = 0.f;
            #pragma unroll
            for (int i = 0; i < 64; ++i) { p[i] = __expf(p[i] - mx); sum += p[i]; }
            const float inv = 1.0f / sum;
            #pragma unroll
            for (int o = 0; o < 64; ++o) sE[L_OT + o * 32 + s] = p[o] * inv;
        } else if (e < 64) {
            const int s = e - 32;
            const float* row = params_r_s + s * R_N;
            float p[8];
            #pragma unroll
            for (int i = 0; i < 2; ++i) {
                float4 v = reinterpret_cast<const float4*>(row)[i];
                p[4*i]=v.x; p[4*i+1]=v.y; p[4*i+2]=v.z; p[4*i+3]=v.w;
            }
            float mx = p[0];
            #pragma unroll
            for (int i = 1; i < 8; ++i) mx = fmaxf(mx, p[i]);
            float sum = 0.f;
            #pragma unroll
            for (int i = 0; i < 8; ++i) { p[i] = __expf(p[i] - mx); sum += p[i]; }
            const float inv = 1.0f / sum;
            #pragma unroll
            for (int r = 0; r < 8; ++r) sE[L_RT + r * 32 + s] = p[r] * inv;
        } else if (e < 96) {
            const int s = e - 64;
            const float* row = params_a_s + s * A_N;
            float p[8];
            #pragma unroll
            for (int i = 0; i < 2; ++i) {
                float4 v = reinterpret_cast<const float4*>(row)[i];
                p[4*i]=v.x; p[4*i+1]=v.y; p[4*i+2]=v.z; p[4*i+3]=v.w;
            }
            float mx = p[0];
            #pragma unroll
            for (int i = 1; i < 8; ++i) mx = fmaxf(mx, p[i]);
            float sum = 0.f;
            #pragma unroll
            for (int i = 0; i < 8; ++i) { p[i] = __expf(p[i] - mx); sum += p[i]; }
            const float inv = 1.0f / sum;
            #pragma unroll
            for (int a = 0; a < 8; ++a) sAT[a * 32 + s] = p[a] * inv;
        } else {
            const int s = e - 96;
            float p[32];
            #pragma unroll
            for (int i = 0; i < 8; ++i) {
                float4 v = reinterpret_cast<const float4*>(params_s)[i];
                p[4*i]=v.x; p[4*i+1]=v.y; p[4*i+2]=v.z; p[4*i+3]=v.w;
            }
            float mx = p[0];
            #pragma unroll
            for (int i = 1; i < 32; ++i) mx = fmaxf(mx, p[i]);
            float sum = 0.f;
            #pragma unroll
            for (int i = 0; i < 32; ++i) { p[i] = __expf(p[i] - mx); sum += p[i]; }
            sE[L_PI + s] = p[s] / sum;
        }
    }
    __syncthreads();
    #pragma unroll 1
    for (int i = tid; i < 2048; i += 256) {
        const int sl2 = i & 31, ra = i >> 5;
        sE[L_RA + i] = sE[L_RT + (ra >> 3) * 32 + sl2] * sAT[(ra & 7) * 32 + sl2];
    }
    __syncthreads();

    // ---------- Phase 2: forward filter, redistribution-free chain ----------
    const int t0 = 2 * lane, t1 = 2 * lane + 1;
    const int o0 = obs[t0 * B_N + b],      o1 = obs[t1 * B_N + b];
    const int r0 = rewards[t0 * B_N + b],  r1 = rewards[t1 * B_N + b];
    const int a0 = actions[t0 * B_N + b],  a1 = actions[t1 * B_N + b];
    const int d0i = dones_i[t0 * B_N + b], d1i = dones_i[t1 * B_N + b];
    const int vpk = (o0 | (r0 << 6) | (a0 << 9)) |
                    ((o1 | (r1 << 6) | (a1 << 9)) << 16);

    const unsigned long long mEv = __ballot(d0i != 0);
    const unsigned long long mOd = __ballot(d1i != 0);
    const int tE = mEv ? 2 * __builtin_ctzll(mEv)     : (1 << 30);
    const int tO = mOd ? 2 * __builtin_ctzll(mOd) + 1 : (1 << 30);
    const int tstar  = tE < tO ? tE : tO;
    const int nsteps = tstar < 128 ? tstar : 128;

    const bool skipA = (regime[b] == 1.0f);
    const int eBase = skipA ? L_RT : L_RA;
    const int eMulR = skipA ? 32 : 256;
    const int eMulA = skipA ? 0 : 32;

    float scp = 1.0f;
    int kpend = 0, ksum = 0;
    f32x4 D1, D2;                 // lane holds u[4g+r] / u[4g+16+r]
    U8 B;                         // w as B-frag (cols replicated)
    bf16x8 tAc0, tAc1;

    unsigned pkc = (unsigned)RLI(vpk, 0);
    unsigned pkn = (unsigned)RLI(vpk, 1);

    // prologue: D = pi ; B_0 = cvtpk(pi .* E_0) ; A_0 frags
    {
        const float4 piL = *(const float4*)(sE + L_PI + c0);
        const float4 piH = *(const float4*)(sE + L_PI + c1);
        D1[0]=piL.x; D1[1]=piL.y; D1[2]=piL.z; D1[3]=piL.w;
        D2[0]=piH.x; D2[1]=piH.y; D2[2]=piH.z; D2[3]=piH.w;
        const unsigned f0 = pkc & 0xffffu;
        const int a0f = (int)((f0 >> 9) & 7u);
        const int ob_ = L_OT + (int)(f0 & 63u) * 32;
        const int rb_ = eBase + (int)((f0 >> 6) & 7u) * eMulR + a0f * eMulA;
        const float4 oL = *(const float4*)(sE + ob_ + c0);
        const float4 oH = *(const float4*)(sE + ob_ + c1);
        const float4 rL = *(const float4*)(sE + rb_ + c0);
        const float4 rH = *(const float4*)(sE + rb_ + c1);
        B.i[0] = cvtpk(D1[0]*oL.x*rL.x, D2[0]*oH.x*rH.x);
        B.i[1] = cvtpk(D1[1]*oL.y*rL.y, D2[1]*oH.y*rH.y);
        B.i[2] = cvtpk(D1[2]*oL.z*rL.z, D2[2]*oH.z*rH.z);
        B.i[3] = cvtpk(D1[3]*oL.w*rL.w, D2[3]*oH.w*rH.w);
        const bf16x8* pA_ = reinterpret_cast<const bf16x8*>(sTH) + a0f * 128 + lane;
        tAc0 = pA_[0]; tAc1 = pA_[64];
    }

    #pragma unroll 1
    for (int t = 0; t < nsteps; ++t) {
        // fields of step t+1 (speculative reads are in-range)
        const unsigned f1 = (t & 1) ? (pkn & 0xffffu) : (pkc >> 16);
        const int a1f = (int)((f1 >> 9) & 7u);
        // prefetch A_{t+1} frags
        const bf16x8* pA_ = reinterpret_cast<const bf16x8*>(sTH) + a1f * 128 + lane;
        const bf16x8 tAn0 = pA_[0], tAn1 = pA_[64];
        // prefetch E_{t+1} rows (16-lane-broadcast loads)
        const int ob_ = L_OT + (int)(f1 & 63u) * 32;
        const int rb_ = eBase + (int)((f1 >> 6) & 7u) * eMulR + a1f * eMulA;
        const float4 oL = *(const float4*)(sE + ob_ + c0);
        const float4 oH = *(const float4*)(sE + ob_ + c1);
        const float4 rL = *(const float4*)(sE + rb_ + c0);
        const float4 rH = *(const float4*)(sE + rb_ + c1);
        // chain: two independent MFMAs -> u_{t+1} rows in-lane
        D1 = __builtin_amdgcn_mfma_f32_16x16x32_bf16(tAc0, B.v, zf4, 0, 0, 0);
        D2 = __builtin_amdgcn_mfma_f32_16x16x32_bf16(tAc1, B.v, zf4, 0, 0, 0);
        // deferred rescale bookkeeping (scp was folded into THIS repack's E)
        ksum += (t + 1 < nsteps) ? kpend : 0;
        const float eL0 = oL.x*rL.x*scp, eL1 = oL.y*rL.y*scp,
                    eL2 = oL.z*rL.z*scp, eL3 = oL.w*rL.w*scp;
        const float eH0 = oH.x*rH.x*scp, eH1 = oH.y*rH.y*scp,
                    eH2 = oH.z*rH.z*scp, eH3 = oH.w*rH.w*scp;
        // chain tail: w_{t+1} = u_{t+1} .* E_{t+1} -> bf16 B-frag (no cross-lane!)
        B.i[0] = cvtpk(D1[0]*eL0, D2[0]*eH0);
        B.i[1] = cvtpk(D1[1]*eL1, D2[1]*eH1);
        B.i[2] = cvtpk(D1[2]*eL2, D2[2]*eH2);
        B.i[3] = cvtpk(D1[3]*eL3, D2[3]*eH3);
        // next-iter rescale factor from this D (state-0 proxy; 1-iter lag)
        const int kb = (RLI(__float_as_int(D1[0]), 0) >> 23) & 255;
        kpend = kb - 127;
        scp = __int_as_float((254 - kb) << 23);
        // rotate
        tAc0 = tAn0; tAc1 = tAn1;
        const unsigned nw = (unsigned)RLI(vpk, (t >> 1) + 2);
        if (t & 1) { pkc = pkn; pkn = nw; }
    }

    // terminal at e = min(t*, 128): u_e is in D1/D2 (rows 4g+r / 4g+16+r)
    {
        const int e  = nsteps;
        const int oe = obs[e * B_N + b];
        const int re = rewards[e * B_N + b];
        const float4 oL = *(const float4*)(sE + L_OT + oe * 32 + c0);
        const float4 oH = *(const float4*)(sE + L_OT + oe * 32 + c1);
        const float4 rL = *(const float4*)(sE + L_RT + re * 32 + c0);
        const float4 rH = *(const float4*)(sE + L_RT + re * 32 + c1);
        float tq = D1[0]*oL.x*rL.x + D1[1]*oL.y*rL.y
                 + D1[2]*oL.z*rL.z + D1[3]*oL.w*rL.w
                 + D2[0]*oH.x*rH.x + D2[1]*oH.y*rH.y
                 + D2[2]*oH.z*rH.z + D2[3]*oH.w*rH.w;
        tq += __shfl_xor(tq, 16);
        tq += __shfl_xor(tq, 32);
        const float result = (float)ksum * 0.69314718055994531f + __logf(tq);
        if (lane == 0) out[b] = result;
    }
}

extern "C" void kernel_launch(void* const* d_in, const int* in_sizes, int n_in,
                              void* d_out, int out_size, void* d_ws, size_t ws_size,
                              hipStream_t stream) {
    (void)in_sizes; (void)n_in; (void)out_size; (void)d_ws; (void)ws_size;
    const float* regime      = (const float*)d_in[0];
    const int*   obs         = (const int*)d_in[1];
    const int*   rewards     = (const int*)d_in[2];
    const int*   dones_i     = (const int*)d_in[3];
    const int*   actions     = (const int*)d_in[4];
    const float* params_s    = (const float*)d_in[5];
    const float* params_s_sa = (const float*)d_in[6];
    const float* params_o_s  = (const float*)d_in[7];
    const float* params_r_s  = (const float*)d_in[8];
    const float* params_a_s  = (const float*)d_in[9];
    float* out = (float*)d_out;

    tam_fused<<<256, 256, 0, stream>>>(regime, obs, rewards, dones_i, actions,
                                       params_s, params_s_sa, params_o_s,
                                       params_r_s, params_a_s, out);
}

// Round 19
// 24.463 us; speedup vs baseline: 1.3943x; 1.3943x over previous
//
#include <hip/hip_runtime.h>

// Problem constants (fixed by the reference)
#define S_N 32
#define O_N 64
#define A_N 8
#define R_N 8
#define B_N 1024
#define T_N 128

// LDS emission block offsets (floats): OT[o][s] | RA[r*8+a][s] | RT[r][s] | PI[s]
#define L_OT 0
#define L_RA 2048
#define L_RT 4096
#define L_PI 4352
#define L_N  4384

typedef float f32x4 __attribute__((ext_vector_type(4)));
typedef short bf16x8 __attribute__((ext_vector_type(8)));

#define RLI(v, l) __builtin_amdgcn_readlane((v), (l))

// v_cvt_pk_bf16_f32: dst = (bf16(lo) low16, bf16(hi) high16) — r17/18-validated
static __device__ __forceinline__ int cvtpk(float lo, float hi) {
    int r;
    asm("v_cvt_pk_bf16_f32 %0, %1, %2" : "=v"(r) : "v"(lo), "v"(hi));
    return r;
}

union U8 { int i[4]; bf16x8 v; };

// Load action A_'s two T B-frags (dest halves): 2 x ds_read_b128, prefetchable
#define LOADT(TH0, TH1, A_) {                                                \
    const bf16x8* p_ = reinterpret_cast<const bf16x8*>(sTH + ((A_) << 7));   \
    TH0 = p_[lane];                                                          \
    TH1 = p_[lane + 64]; }

// Emission factor products for this lane's state pair (h0, h0+16); low 16
// bits of PKW. Off the u-dependency path (computed at prefetch time).
#define LOADE(ELO, EHI, PKW) {                                               \
    const unsigned pk_ = (PKW);                                              \
    const int ob_ = L_OT + (int)(pk_ & 63u) * 32 + h0;                       \
    const int rb_ = eBase + (int)((pk_ >> 6) & 7u) * eMulR                   \
                  + (int)((pk_ >> 9) & 7u) * eMulA + h0;                     \
    ELO = sE[ob_] * sE[rb_];                                                 \
    EHI = sE[ob_ + 16] * sE[rb_ + 16]; }

// One HMM step on the MATRIX CORE with permuted-k state order (r16-validated):
// w = u.*E1 -> cvt_pk_bf16 pack (1 instr) -> 4 bpermute pulls build the
// A-frag -> two mfma_f32_16x16x32_bf16 -> next (ulo, uhi) directly.
#define STEP(ELO, EHI, TH0, TH1) {                                           \
    const int pw = cvtpk(ulo * (ELO), uhi * (EHI));                          \
    U8 A_;                                                                   \
    A_.i[0] = __builtin_amdgcn_ds_bpermute(bpb,      pw);                    \
    A_.i[1] = __builtin_amdgcn_ds_bpermute(bpb + 4,  pw);                    \
    A_.i[2] = __builtin_amdgcn_ds_bpermute(bpb + 8,  pw);                    \
    A_.i[3] = __builtin_amdgcn_ds_bpermute(bpb + 12, pw);                    \
    const f32x4 d0 = __builtin_amdgcn_mfma_f32_16x16x32_bf16(A_.v, TH0, zf4, 0, 0, 0); \
    const f32x4 d1 = __builtin_amdgcn_mfma_f32_16x16x32_bf16(A_.v, TH1, zf4, 0, 0, 0); \
    ulo = d0[0]; uhi = d1[0];                                                \
}

// exact power-of-two rescale (state-0 proxy; fp32 u + bf16 w tolerate a
// 4-step cadence — exponent range is fp32's)
#define RESCALE() {                                                          \
    const int ub = RLI(__float_as_int(ulo), 0);                              \
    const int kb = (ub >> 23) & 255;                                         \
    const float sc_ = __int_as_float((254 - kb) << 23);                      \
    ulo *= sc_; uhi *= sc_;                                                  \
    ksum += kb - 127; }

// SINGLE fused kernel: per-block LDS table build, then the depth-1 prefetch
// A/B loop with the permuted-k MFMA step core. 4 waves/block, 1 episode/wave.
__global__ __launch_bounds__(256) void tam_fused(
    const float* __restrict__ regime,
    const int*   __restrict__ obs,
    const int*   __restrict__ rewards,
    const int*   __restrict__ dones_i,   // float32 0/1 read as int bits
    const int*   __restrict__ actions,
    const float* __restrict__ params_s,
    const float* __restrict__ params_s_sa,
    const float* __restrict__ params_o_s,
    const float* __restrict__ params_r_s,
    const float* __restrict__ params_a_s,
    float* __restrict__ out)
{
    __shared__ uint4 sTH[1024];          // 16 KB bf16 T, B-frag permuted-k layout
    __shared__ float sE[L_N];            // 17.1 KB emission block
    __shared__ float sAT[256];           // action prior (feeds RA)
    const int tid  = threadIdx.x;
    const int lane = tid & 63;
    const int wid  = tid >> 6;
    const int h0   = lane & 15;          // this lane's low state
    const int g    = lane >> 4;          // A-frag k-octet group (0..3)
    const int bpb  = g * 16;             // bpermute byte addr of src lane 4g
    const int b    = blockIdx.x * 4 + wid;
    const f32x4 zf4 = {0.f, 0.f, 0.f, 0.f};

    // ---------- Phase 1: build tables in LDS (r16-validated) ----------
    if (tid < 128) {
        // two transition-row softmaxes each; scatter bf16 into the B-frag
        // layout with permuted k: row s sits at k = 2*(s&15) + (s>>4).
        unsigned short* sTHh = reinterpret_cast<unsigned short*>(sTH);
        #pragma unroll 1
        for (int rr = 0; rr < 2; ++rr) {
            const int idx = 2 * tid + rr;
            const int s = idx >> 3, a = idx & 7;
            const float* row = params_s_sa + (s * A_N + a) * S_N;
            float p[32];
            #pragma unroll
            for (int i = 0; i < 8; ++i) {
                float4 v = reinterpret_cast<const float4*>(row)[i];
                p[4*i]=v.x; p[4*i+1]=v.y; p[4*i+2]=v.z; p[4*i+3]=v.w;
            }
            float mx = p[0];
            #pragma unroll
            for (int i = 1; i < 32; ++i) mx = fmaxf(mx, p[i]);
            float sum = 0.f;
            #pragma unroll
            for (int i = 0; i < 32; ++i) { p[i] = __expf(p[i] - mx); sum += p[i]; }
            const float inv = 1.0f / sum;
            const int ks = 2 * (s & 15) + (s >> 4);
            const int gk = ks >> 3, e8 = ks & 7;
            #pragma unroll
            for (int d = 0; d < 32; ++d) {
                const unsigned bits = __float_as_uint(p[d] * inv) + 0x8000u;
                const int l2 = 16 * gk + (d & 15);
                sTHh[((a * 2 + (d >> 4)) * 64 + l2) * 8 + e8] =
                    (unsigned short)(bits >> 16);
            }
        }
    } else {
        const int e = tid - 128;
        if (e < 32) {
            // observation emission: softmax over O (64); OT[o][s]
            const int s = e;
            const float* row = params_o_s + s * O_N;
            float p[64];
            #pragma unroll
            for (int i = 0; i < 16; ++i) {
                float4 v = reinterpret_cast<const float4*>(row)[i];
                p[4*i]=v.x; p[4*i+1]=v.y; p[4*i+2]=v.z; p[4*i+3]=v.w;
            }
            float mx = p[0];
            #pragma unroll
            for (int i = 1; i < 64; ++i) mx = fmaxf(mx, p[i]);
            float sum = 0.f;
            #pragma unroll
            for (int i = 0; i < 64; ++i) { p[i] = __expf(p[i] - mx); sum += p[i]; }
            const float inv = 1.0f / sum;
            #pragma unroll
            for (int o = 0; o < 64; ++o) sE[L_OT + o * 32 + s] = p[o] * inv;
        } else if (e < 64) {
            // reward emission: RT[r][s]
            const int s = e - 32;
            const float* row = params_r_s + s * R_N;
            float p[8];
            #pragma unroll
            for (int i = 0; i < 2; ++i) {
                float4 v = reinterpret_cast<const float4*>(row)[i];
                p[4*i]=v.x; p[4*i+1]=v.y; p[4*i+2]=v.z; p[4*i+3]=v.w;
            }
            float mx = p[0];
            #pragma unroll
            for (int i = 1; i < 8; ++i) mx = fmaxf(mx, p[i]);
            float sum = 0.f;
            #pragma unroll
            for (int i = 0; i < 8; ++i) { p[i] = __expf(p[i] - mx); sum += p[i]; }
            const float inv = 1.0f / sum;
            #pragma unroll
            for (int r = 0; r < 8; ++r) sE[L_RT + r * 32 + s] = p[r] * inv;
        } else if (e < 96) {
            // action prior: AT[a][s] (feeds RA only)
            const int s = e - 64;
            const float* row = params_a_s + s * A_N;
            float p[8];
            #pragma unroll
            for (int i = 0; i < 2; ++i) {
                float4 v = reinterpret_cast<const float4*>(row)[i];
                p[4*i]=v.x; p[4*i+1]=v.y; p[4*i+2]=v.z; p[4*i+3]=v.w;
            }
            float mx = p[0];
            #pragma unroll
            for (int i = 1; i < 8; ++i) mx = fmaxf(mx, p[i]);
            float sum = 0.f;
            #pragma unroll
            for (int i = 0; i < 8; ++i) { p[i] = __expf(p[i] - mx); sum += p[i]; }
            const float inv = 1.0f / sum;
            #pragma unroll
            for (int a = 0; a < 8; ++a) sAT[a * 32 + s] = p[a] * inv;
        } else {
            // pi = softmax(params_s): redundant per-thread, write own element
            const int s = e - 96;
            float p[32];
            #pragma unroll
            for (int i = 0; i < 8; ++i) {
                float4 v = reinterpret_cast<const float4*>(params_s)[i];
                p[4*i]=v.x; p[4*i+1]=v.y; p[4*i+2]=v.z; p[4*i+3]=v.w;
            }
            float mx = p[0];
            #pragma unroll
            for (int i = 1; i < 32; ++i) mx = fmaxf(mx, p[i]);
            float sum = 0.f;
            #pragma unroll
            for (int i = 0; i < 32; ++i) { p[i] = __expf(p[i] - mx); sum += p[i]; }
            sE[L_PI + s] = p[s] / sum;
        }
    }
    __syncthreads();
    // RA[r*8+a][s] = RT[r][s] * AT[a][s]
    #pragma unroll 1
    for (int i = tid; i < 2048; i += 256) {
        const int sl2 = i & 31, ra = i >> 5;
        sE[L_RA + i] = sE[L_RT + (ra >> 3) * 32 + sl2] * sAT[(ra & 7) * 32 + sl2];
    }
    __syncthreads();

    // ---------- Phase 2: forward filter (r16 loop, cvtpk pack, 4-step rescale)
    const int t0 = 2 * lane, t1 = 2 * lane + 1;
    const int o0 = obs[t0 * B_N + b],      o1 = obs[t1 * B_N + b];
    const int r0 = rewards[t0 * B_N + b],  r1 = rewards[t1 * B_N + b];
    const int a0 = actions[t0 * B_N + b],  a1 = actions[t1 * B_N + b];
    const int d0i = dones_i[t0 * B_N + b], d1i = dones_i[t1 * B_N + b];
    const int vpk = (o0 | (r0 << 6) | (a0 << 9)) |
                    ((o1 | (r1 << 6) | (a1 << 9)) << 16);

    // first-done step t* via ballot (per-wave; no done checks in hot loop)
    const unsigned long long mEv = __ballot(d0i != 0);
    const unsigned long long mOd = __ballot(d1i != 0);
    const int tE = mEv ? 2 * __builtin_ctzll(mEv)     : (1 << 30);
    const int tO = mOd ? 2 * __builtin_ctzll(mOd) + 1 : (1 << 30);
    const int tstar  = tE < tO ? tE : tO;
    const int nsteps = tstar < 128 ? tstar : 128;

    // regime==1 -> action term excluded every step: use RT table (a ignored)
    const bool skipA = (regime[b] == 1.0f);
    const int eBase = skipA ? L_RT : L_RA;
    const int eMulR = skipA ? 32 : 256;
    const int eMulA = skipA ? 0 : 32;

    float ulo = sE[L_PI + h0];
    float uhi = sE[L_PI + h0 + 16];
    int ksum = 0;
    float eloA, ehiA, eloB, ehiB;
    bf16x8 thA0, thA1, thB0, thB1;

    unsigned pkc = (unsigned)RLI(vpk, 0);
    unsigned pkn = (unsigned)RLI(vpk, 1);
    LOADE(eloA, ehiA, pkc);
    LOADT(thA0, thA1, (int)((pkc >> 9) & 7u));

    const int npairs = nsteps >> 1;
    #pragma unroll 1
    for (int i = 0; i < npairs; ++i) {
        // prefetch step 2i+1 (B), compute step 2i (A)
        LOADE(eloB, ehiB, pkc >> 16);
        LOADT(thB0, thB1, (int)((pkc >> 25) & 7u));
        STEP(eloA, ehiA, thA0, thA1);
        // prefetch step 2i+2 (next A), compute step 2i+1 (B)
        LOADE(eloA, ehiA, pkn);
        LOADT(thA0, thA1, (int)((pkn >> 9) & 7u));
        STEP(eloB, ehiB, thB0, thB1);
        // rotate packed indices (readlane lane wraps mod 64; overflow unused)
        pkc = pkn;
        pkn = (unsigned)RLI(vpk, i + 2);
        // rescale every 2 pairs (4 steps) — fp32 exponent headroom suffices
        if (i & 1) { RESCALE(); }
    }

    if (nsteps & 1) {           // leftover even-index step (data already staged)
        STEP(eloA, ehiA, thA0, thA1);
    }

    // terminal contribution at e = min(t*, 128): OT*RT only (no action term)
    {
        const int e  = nsteps;
        const int oe = obs[e * B_N + b];
        const int re = rewards[e * B_N + b];
        const int ob = L_OT + oe * 32 + h0;
        const int rb = L_RT + re * 32 + h0;
        float t = ulo * sE[ob] * sE[rb] + uhi * sE[ob + 16] * sE[rb + 16];
        t += __shfl_xor(t, 1, 16);
        t += __shfl_xor(t, 2, 16);
        t += __shfl_xor(t, 4, 16);
        t += __shfl_xor(t, 8, 16);
        const float result = (float)ksum * 0.69314718055994531f + __logf(t);
        if (lane == 0) out[b] = result;
    }
}

extern "C" void kernel_launch(void* const* d_in, const int* in_sizes, int n_in,
                              void* d_out, int out_size, void* d_ws, size_t ws_size,
                              hipStream_t stream) {
    (void)in_sizes; (void)n_in; (void)out_size; (void)d_ws; (void)ws_size;
    const float* regime      = (const float*)d_in[0];
    const int*   obs         = (const int*)d_in[1];
    const int*   rewards     = (const int*)d_in[2];
    const int*   dones_i     = (const int*)d_in[3];
    const int*   actions     = (const int*)d_in[4];
    const float* params_s    = (const float*)d_in[5];
    const float* params_s_sa = (const float*)d_in[6];
    const float* params_o_s  = (const float*)d_in[7];
    const float* params_r_s  = (const float*)d_in[8];
    const float* params_a_s  = (const float*)d_in[9];
    float* out = (float*)d_out;

    tam_fused<<<256, 256, 0, stream>>>(regime, obs, rewards, dones_i, actions,
                                       params_s, params_s_sa, params_o_s,
                                       params_r_s, params_a_s, out);
}